// Round 1
// baseline (137.217 us; speedup 1.0000x reference)
//
#include <hip/hip_runtime.h>

// Problem constants (fixed shapes from the reference).
constexpr int B = 2, C = 320, H = 128, W = 240;
constexpr int G = 40, CPG = 8, MAXD = 48;
constexpr int HW = H * W;
constexpr int NROW = B * G * H;        // 10240 (b,g,h) rows
constexpr int ROWS_PER_BLOCK = 4;      // one wave (64 lanes) per row
constexpr int W4 = W / 4;              // 60 float4 per channel row

// out[b,g,d,h,x] = (1/CPG) * sum_k L[b, g*CPG+k, h, x] * R[b, g*CPG+k, h, x-d]  (x>=d, else 0)
__global__ __launch_bounds__(256) void gwc_volume_kernel(
    const float* __restrict__ left, const float* __restrict__ right,
    float* __restrict__ out)
{
    const int tid  = threadIdx.x;
    const int wv   = tid >> 6;   // wave id within block -> which row
    const int lane = tid & 63;
    const int row  = blockIdx.x * ROWS_PER_BLOCK + wv;

    const int h  = row % H;
    const int bg = row / H;
    const int g  = bg % G;
    const int b  = bg / G;

    // Per-wave staged right row: 8 channels x 240 floats = 480 float4 (7.7 KB)
    __shared__ float4 sR4[ROWS_PER_BLOCK][CPG * W4 + 2];

    const size_t in_base = ((size_t)(b * C + g * CPG) * H + h) * (size_t)W;

    // ---- stage the right row into LDS (coalesced float4 loads) ----
    #pragma unroll
    for (int i = 0; i < 8; ++i) {
        int j = i * 64 + lane;           // 0..479 float4 index (k*60 + x4)
        if (j < CPG * W4) {
            int k  = j / W4;
            int x4 = j - k * W4;
            const float4* src =
                reinterpret_cast<const float4*>(right + in_base + (size_t)k * HW);
            sR4[wv][j] = src[x4];
        }
    }
    __syncthreads();

    const int t = lane;                  // x-tile index, x = 4t..4t+3
    if (t >= W4) return;                 // lanes 60..63 only help staging

    // ---- left fragment in registers: 8 channels x 4 x-positions ----
    float L[CPG][4];
    #pragma unroll
    for (int k = 0; k < CPG; ++k) {
        const float4 lv = *reinterpret_cast<const float4*>(
            left + in_base + (size_t)k * HW + 4 * t);
        L[k][0] = lv.x; L[k][1] = lv.y; L[k][2] = lv.z; L[k][3] = lv.w;
    }

    const float4* sr = &sR4[wv][0];
    float* outp = out + (((size_t)(b * G + g) * MAXD) * H + h) * (size_t)W + 4 * t;

    // ---- 12 disparity groups of 4; A = x_base - d_base = 4*(t - dg) ----
    #pragma unroll
    for (int dg = 0; dg < MAXD / 4; ++dg) {
        float acc[4][4];
        #pragma unroll
        for (int dd = 0; dd < 4; ++dd)
            #pragma unroll
            for (int xx = 0; xx < 4; ++xx) acc[dd][xx] = 0.f;

        if (t >= dg) {                   // t < dg: whole tile in the zero wedge
            #pragma unroll
            for (int k = 0; k < CPG; ++k) {
                const int base = k * W4 + (t - dg);
                const float4 hi = sr[base];                  // R[A .. A+3]
                float4 lo;
                if (t > dg) lo = sr[base - 1];               // R[A-4 .. A-1]
                else        lo = make_float4(0.f, 0.f, 0.f, 0.f); // x<d -> zeros
                float win[8];
                win[0] = lo.x; win[1] = lo.y; win[2] = lo.z; win[3] = lo.w;
                win[4] = hi.x; win[5] = hi.y; win[6] = hi.z; win[7] = hi.w;
                // out index math: r-index = A + xx - dd -> win[4 + xx - dd]
                #pragma unroll
                for (int dd = 0; dd < 4; ++dd)
                    #pragma unroll
                    for (int xx = 0; xx < 4; ++xx)
                        acc[dd][xx] += L[k][xx] * win[4 + xx - dd];
            }
        }

        #pragma unroll
        for (int dd = 0; dd < 4; ++dd) {
            float4 o;
            o.x = acc[dd][0] * 0.125f;
            o.y = acc[dd][1] * 0.125f;
            o.z = acc[dd][2] * 0.125f;
            o.w = acc[dd][3] * 0.125f;
            *reinterpret_cast<float4*>(outp + (size_t)(dg * 4 + dd) * HW) = o;
        }
    }
}

extern "C" void kernel_launch(void* const* d_in, const int* in_sizes, int n_in,
                              void* d_out, int out_size, void* d_ws, size_t ws_size,
                              hipStream_t stream) {
    const float* left  = (const float*)d_in[0];
    const float* right = (const float*)d_in[1];
    float* out = (float*)d_out;

    dim3 grid(NROW / ROWS_PER_BLOCK);   // 2560 blocks
    dim3 block(256);                    // 4 waves, one (b,g,h) row each
    hipLaunchKernelGGL(gwc_volume_kernel, grid, block, 0, stream,
                       left, right, out);
}

// Round 3
// 135.057 us; speedup vs baseline: 1.0160x; 1.0160x over previous
//
#include <hip/hip_runtime.h>

// Problem constants (fixed shapes from the reference).
constexpr int B = 2, C = 320, H = 128, W = 240;
constexpr int G = 40, CPG = 8, MAXD = 48;
constexpr int HW = H * W;
constexpr int NROW = B * G * H;        // 10240 (b,g,h) rows
constexpr int ROWS_PER_BLOCK = 4;      // one wave (64 lanes) per row
constexpr int W4 = W / 4;              // 60 float4 per channel row

// Native clang vector type: __builtin_nontemporal_* accepts these
// (it rejects HIP_vector_type aka float4).
typedef float f32x4 __attribute__((ext_vector_type(4)));

// out[b,g,d,h,x] = (1/CPG) * sum_k L[b, g*CPG+k, h, x] * R[b, g*CPG+k, h, x-d]  (x>=d, else 0)
__global__ __launch_bounds__(256) void gwc_volume_kernel(
    const float* __restrict__ left, const float* __restrict__ right,
    float* __restrict__ out)
{
    const int tid  = threadIdx.x;
    const int wv   = tid >> 6;   // wave id within block -> which row
    const int lane = tid & 63;
    const int row  = blockIdx.x * ROWS_PER_BLOCK + wv;

    const int h  = row % H;
    const int bg = row / H;
    const int g  = bg % G;
    const int b  = bg / G;

    // Per-wave staged right row: 8 channels x 240 floats = 480 float4 (7.7 KB).
    // Each wave touches ONLY its own sR4[wv] slice -> no cross-wave barrier needed.
    __shared__ f32x4 sR4[ROWS_PER_BLOCK][CPG * W4 + 2];

    const size_t in_base = ((size_t)(b * C + g * CPG) * H + h) * (size_t)W;

    // ---- stage the right row into LDS (coalesced nontemporal 16B loads) ----
    #pragma unroll
    for (int i = 0; i < 8; ++i) {
        int j = i * 64 + lane;           // 0..479 float4 index (k*60 + x4)
        if (j < CPG * W4) {
            int k  = j / W4;
            int x4 = j - k * W4;
            const f32x4* src =
                reinterpret_cast<const f32x4*>(right + in_base + (size_t)k * HW);
            sR4[wv][j] = __builtin_nontemporal_load(&src[x4]);
        }
    }
    // Wave-local ordering: make sure our ds_writes have landed before ds_reads.
    asm volatile("s_waitcnt lgkmcnt(0)" ::: "memory");

    const int t = lane;                  // x-tile index, x = 4t..4t+3
    if (t >= W4) return;                 // lanes 60..63 only help staging

    // ---- left fragment in registers: 8 channels x 4 x-positions (read-once -> nt) ----
    float L[CPG][4];
    #pragma unroll
    for (int k = 0; k < CPG; ++k) {
        const f32x4 lv = __builtin_nontemporal_load(
            reinterpret_cast<const f32x4*>(left + in_base + (size_t)k * HW + 4 * t));
        L[k][0] = lv.x; L[k][1] = lv.y; L[k][2] = lv.z; L[k][3] = lv.w;
    }

    const f32x4* sr = &sR4[wv][0];
    float* outp = out + (((size_t)(b * G + g) * MAXD) * H + h) * (size_t)W + 4 * t;

    // ---- 12 disparity groups of 4; A = x_base - d_base = 4*(t - dg) ----
    #pragma unroll
    for (int dg = 0; dg < MAXD / 4; ++dg) {
        float acc[4][4];
        #pragma unroll
        for (int dd = 0; dd < 4; ++dd)
            #pragma unroll
            for (int xx = 0; xx < 4; ++xx) acc[dd][xx] = 0.f;

        if (t >= dg) {                   // t < dg: whole tile in the zero wedge
            #pragma unroll
            for (int k = 0; k < CPG; ++k) {
                const int base = k * W4 + (t - dg);
                const f32x4 hi = sr[base];                   // R[A .. A+3]
                f32x4 lo;
                if (t > dg) lo = sr[base - 1];               // R[A-4 .. A-1]
                else        lo = (f32x4){0.f, 0.f, 0.f, 0.f}; // x<d -> zeros
                float win[8];
                win[0] = lo.x; win[1] = lo.y; win[2] = lo.z; win[3] = lo.w;
                win[4] = hi.x; win[5] = hi.y; win[6] = hi.z; win[7] = hi.w;
                // out index math: r-index = A + xx - dd -> win[4 + xx - dd]
                #pragma unroll
                for (int dd = 0; dd < 4; ++dd)
                    #pragma unroll
                    for (int xx = 0; xx < 4; ++xx)
                        acc[dd][xx] += L[k][xx] * win[4 + xx - dd];
            }
        }

        #pragma unroll
        for (int dd = 0; dd < 4; ++dd) {
            f32x4 o;
            o.x = acc[dd][0] * 0.125f;
            o.y = acc[dd][1] * 0.125f;
            o.z = acc[dd][2] * 0.125f;
            o.w = acc[dd][3] * 0.125f;
            // Streaming write-once output: keep it out of L2 (nontemporal).
            __builtin_nontemporal_store(
                o, reinterpret_cast<f32x4*>(outp + (size_t)(dg * 4 + dd) * HW));
        }
    }
}

extern "C" void kernel_launch(void* const* d_in, const int* in_sizes, int n_in,
                              void* d_out, int out_size, void* d_ws, size_t ws_size,
                              hipStream_t stream) {
    const float* left  = (const float*)d_in[0];
    const float* right = (const float*)d_in[1];
    float* out = (float*)d_out;

    dim3 grid(NROW / ROWS_PER_BLOCK);   // 2560 blocks
    dim3 block(256);                    // 4 waves, one (b,g,h) row each
    hipLaunchKernelGGL(gwc_volume_kernel, grid, block, 0, stream,
                       left, right, out);
}

// Round 4
// 131.862 us; speedup vs baseline: 1.0406x; 1.0242x over previous
//
#include <hip/hip_runtime.h>

// Problem constants (fixed shapes from the reference).
constexpr int B = 2, C = 320, H = 128, W = 240;
constexpr int G = 40, CPG = 8, MAXD = 48;
constexpr int HW = H * W;
constexpr int NROW = B * G * H;        // 10240 (b,g,h) rows
constexpr int ROWS_PER_BLOCK = 8;      // 8 waves/block, one row each, consecutive h
constexpr int W4 = W / 4;              // 60 float4 per channel row

// Native clang vector type: __builtin_nontemporal_* accepts these
// (it rejects HIP_vector_type aka float4).
typedef float f32x4 __attribute__((ext_vector_type(4)));

// out[b,g,d,h,x] = (1/CPG) * sum_k L[b, g*CPG+k, h, x] * R[b, g*CPG+k, h, x-d]  (x>=d, else 0)
//
// Write-locality design: a block's 8 waves cover 8 CONSECUTIVE h rows of one
// (b,g) (8 | H so tiles never straddle). A __syncthreads() per disparity-group
// keeps the 8 waves in lockstep, so each d-slice receives one temporally
// clustered 8x960B = 7.7KB contiguous write burst instead of scattered 960B
// bursts from unsynchronized waves -> better DRAM row locality.
__global__ __launch_bounds__(512) void gwc_volume_kernel(
    const float* __restrict__ left, const float* __restrict__ right,
    float* __restrict__ out)
{
    const int tid  = threadIdx.x;
    const int wv   = tid >> 6;   // wave id within block -> which row (0..7)
    const int lane = tid & 63;
    const int row  = blockIdx.x * ROWS_PER_BLOCK + wv;

    const int h  = row % H;
    const int bg = row / H;
    const int g  = bg % G;
    const int b  = bg / G;

    // Per-wave staged right row: 8 channels x 240 floats = 480 float4 (7.7 KB).
    // Each wave touches ONLY its own sR4[wv] slice. 8 x 7.71 KB = 61.7 KB/block.
    __shared__ f32x4 sR4[ROWS_PER_BLOCK][CPG * W4 + 2];

    const size_t in_base = ((size_t)(b * C + g * CPG) * H + h) * (size_t)W;

    // ---- stage the right row into LDS (coalesced nontemporal 16B loads) ----
    #pragma unroll
    for (int i = 0; i < 8; ++i) {
        int j = i * 64 + lane;           // 0..479 float4 index (k*60 + x4)
        if (j < CPG * W4) {
            int k  = j / W4;
            int x4 = j - k * W4;
            const f32x4* src =
                reinterpret_cast<const f32x4*>(right + in_base + (size_t)k * HW);
            sR4[wv][j] = __builtin_nontemporal_load(&src[x4]);
        }
    }
    // Wave-local ordering: our ds_writes must land before our ds_reads.
    asm volatile("s_waitcnt lgkmcnt(0)" ::: "memory");

    const int t = lane;                  // x-tile index, x = 4t..4t+3
    // NOTE: lanes 60..63 stay in the kernel (exec-masked per phase) so the
    // whole wave participates in the per-dg barriers.
    const bool active = (t < W4);

    // ---- left fragment in registers: 8 channels x 4 x-positions (read-once -> nt) ----
    float L[CPG][4];
    if (active) {
        #pragma unroll
        for (int k = 0; k < CPG; ++k) {
            const f32x4 lv = __builtin_nontemporal_load(
                reinterpret_cast<const f32x4*>(left + in_base + (size_t)k * HW + 4 * t));
            L[k][0] = lv.x; L[k][1] = lv.y; L[k][2] = lv.z; L[k][3] = lv.w;
        }
    }

    const f32x4* sr = &sR4[wv][0];
    float* outp = out + (((size_t)(b * G + g) * MAXD) * H + h) * (size_t)W + 4 * t;

    // ---- 12 disparity groups of 4; A = x_base - d_base = 4*(t - dg) ----
    #pragma unroll 2
    for (int dg = 0; dg < MAXD / 4; ++dg) {
        // Temporal write alignment across the block's 8 waves.
        __syncthreads();

        float acc[4][4];
        #pragma unroll
        for (int dd = 0; dd < 4; ++dd)
            #pragma unroll
            for (int xx = 0; xx < 4; ++xx) acc[dd][xx] = 0.f;

        if (active && t >= dg) {         // t < dg: whole tile in the zero wedge
            #pragma unroll
            for (int k = 0; k < CPG; ++k) {
                const int base = k * W4 + (t - dg);
                const f32x4 hi = sr[base];                   // R[A .. A+3]
                f32x4 lo;
                if (t > dg) lo = sr[base - 1];               // R[A-4 .. A-1]
                else        lo = (f32x4){0.f, 0.f, 0.f, 0.f}; // x<d -> zeros
                float win[8];
                win[0] = lo.x; win[1] = lo.y; win[2] = lo.z; win[3] = lo.w;
                win[4] = hi.x; win[5] = hi.y; win[6] = hi.z; win[7] = hi.w;
                // out index math: r-index = A + xx - dd -> win[4 + xx - dd]
                #pragma unroll
                for (int dd = 0; dd < 4; ++dd)
                    #pragma unroll
                    for (int xx = 0; xx < 4; ++xx)
                        acc[dd][xx] += L[k][xx] * win[4 + xx - dd];
            }
        }

        if (active) {
            #pragma unroll
            for (int dd = 0; dd < 4; ++dd) {
                f32x4 o;
                o.x = acc[dd][0] * 0.125f;
                o.y = acc[dd][1] * 0.125f;
                o.z = acc[dd][2] * 0.125f;
                o.w = acc[dd][3] * 0.125f;
                // Streaming write-once output: nontemporal.
                __builtin_nontemporal_store(
                    o, reinterpret_cast<f32x4*>(outp + (size_t)(dg * 4 + dd) * HW));
            }
        }
    }
}

extern "C" void kernel_launch(void* const* d_in, const int* in_sizes, int n_in,
                              void* d_out, int out_size, void* d_ws, size_t ws_size,
                              hipStream_t stream) {
    const float* left  = (const float*)d_in[0];
    const float* right = (const float*)d_in[1];
    float* out = (float*)d_out;

    dim3 grid(NROW / ROWS_PER_BLOCK);   // 1280 blocks
    dim3 block(512);                    // 8 waves, 8 consecutive h rows of one (b,g)
    hipLaunchKernelGGL(gwc_volume_kernel, grid, block, 0, stream,
                       left, right, out);
}

// Round 5
// 120.727 us; speedup vs baseline: 1.1366x; 1.0922x over previous
//
#include <hip/hip_runtime.h>

// Problem constants (fixed shapes from the reference).
constexpr int B = 2, C = 320, H = 128, W = 240;
constexpr int G = 40, CPG = 8, MAXD = 48;
constexpr int HW = H * W;
constexpr int NROW = B * G * H;        // 10240 (b,g,h) rows
constexpr int ROWS_PER_BLOCK = 8;      // 8 waves/block, one row each, consecutive h
constexpr int W4 = W / 4;              // 60 float4 per channel row

typedef float f32x4 __attribute__((ext_vector_type(4)));

// Address-space-qualified void types for global_load_lds.
typedef const __attribute__((address_space(1))) void g_void;
typedef __attribute__((address_space(3))) void lds_void;

// out[b,g,d,h,x] = (1/CPG) * sum_k L[b, g*CPG+k, h, x] * R[b, g*CPG+k, h, x-d]  (x>=d, else 0)
//
// R5 changes vs R4:
//  - L loads issue FIRST; R staged via global_load_lds (direct HBM->LDS DMA).
//    Both batches in flight concurrently; ONE vmcnt(0) before compute.
//    (R4 serialized: R-load -> ds_write -> lgkm drain -> L-load -> compute.)
//  - Per-dg __syncthreads() (which drains vmcnt(0), stalling all waves on
//    store acks 12x/block) replaced by raw s_barrier: keeps the 8-wave write
//    clustering, drops the drain. Waves share no LDS -> no ordering needed.
__global__ __launch_bounds__(512) void gwc_volume_kernel(
    const float* __restrict__ left, const float* __restrict__ right,
    float* __restrict__ out)
{
    const int tid  = threadIdx.x;
    const int wv   = tid >> 6;   // wave id within block -> which row (0..7)
    const int lane = tid & 63;
    const int row  = blockIdx.x * ROWS_PER_BLOCK + wv;

    const int h  = row % H;
    const int bg = row / H;
    const int g  = bg % G;
    const int b  = bg / G;

    // Per-wave staged right row: 8 channels x 60 float4 = 480 float4 (7.68 KB).
    // LINEAR layout (global_load_lds writes base + lane*16, no padding allowed).
    __shared__ f32x4 sR4[ROWS_PER_BLOCK][CPG * W4];

    const size_t in_base = ((size_t)(b * C + g * CPG) * H + h) * (size_t)W;

    const int t = lane;                  // x-tile index, x = 4t..4t+3
    const bool active = (t < W4);        // lanes 60..63 help staging + barriers only

    // ---- issue LEFT loads first (registers), so they fly with R staging ----
    f32x4 Lv[CPG];
    if (active) {
        #pragma unroll
        for (int k = 0; k < CPG; ++k)
            Lv[k] = __builtin_nontemporal_load(
                reinterpret_cast<const f32x4*>(left + in_base + (size_t)k * HW + 4 * t));
    }

    // ---- stage RIGHT row: direct HBM -> LDS, 8 x (64 lanes x 16 B) chunks ----
    // LDS dest is wave-uniform base + lane*16; our linear j = i*64+lane matches.
    #pragma unroll
    for (int i = 0; i < 8; ++i) {
        const int j = i * 64 + lane;     // float4 index: j = k*60 + x4
        if (j < CPG * W4) {
            const int k  = j / W4;
            const int x4 = j - k * W4;
            const float* src = right + in_base + (size_t)k * HW + 4 * x4;
            char* dst = (char*)&sR4[wv][0] + (size_t)i * 1024;
            __builtin_amdgcn_global_load_lds((g_void*)src, (lds_void*)dst, 16, 0, 0);
        }
    }

    // One drain for BOTH batches (L regs + LDS staging), then compute.
    asm volatile("s_waitcnt vmcnt(0)" ::: "memory");
    __builtin_amdgcn_sched_barrier(0);

    const f32x4* sr = &sR4[wv][0];
    float* outp = out + (((size_t)(b * G + g) * MAXD) * H + h) * (size_t)W + 4 * t;

    // ---- 12 disparity groups of 4; A = x_base - d_base = 4*(t - dg) ----
    #pragma unroll 2
    for (int dg = 0; dg < MAXD / 4; ++dg) {
        // Temporal write clustering across the block's 8 waves — raw barrier,
        // NO vmcnt drain (stores stay in flight).
        __builtin_amdgcn_s_barrier();

        float acc[4][4];
        #pragma unroll
        for (int dd = 0; dd < 4; ++dd)
            #pragma unroll
            for (int xx = 0; xx < 4; ++xx) acc[dd][xx] = 0.f;

        if (active && t >= dg) {         // t < dg: whole tile in the zero wedge
            #pragma unroll
            for (int k = 0; k < CPG; ++k) {
                const int base = k * W4 + (t - dg);
                const f32x4 hi = sr[base];                   // R[A .. A+3]
                f32x4 lo;
                if (t > dg) lo = sr[base - 1];               // R[A-4 .. A-1]
                else        lo = (f32x4){0.f, 0.f, 0.f, 0.f}; // x<d -> zeros
                float win[8];
                win[0] = lo.x; win[1] = lo.y; win[2] = lo.z; win[3] = lo.w;
                win[4] = hi.x; win[5] = hi.y; win[6] = hi.z; win[7] = hi.w;
                // r-index = A + xx - dd -> win[4 + xx - dd]
                #pragma unroll
                for (int dd = 0; dd < 4; ++dd)
                    #pragma unroll
                    for (int xx = 0; xx < 4; ++xx)
                        acc[dd][xx] += Lv[k][xx] * win[4 + xx - dd];
            }
        }

        if (active) {
            #pragma unroll
            for (int dd = 0; dd < 4; ++dd) {
                f32x4 o;
                o.x = acc[dd][0] * 0.125f;
                o.y = acc[dd][1] * 0.125f;
                o.z = acc[dd][2] * 0.125f;
                o.w = acc[dd][3] * 0.125f;
                __builtin_nontemporal_store(
                    o, reinterpret_cast<f32x4*>(outp + (size_t)(dg * 4 + dd) * HW));
            }
        }
    }
}

extern "C" void kernel_launch(void* const* d_in, const int* in_sizes, int n_in,
                              void* d_out, int out_size, void* d_ws, size_t ws_size,
                              hipStream_t stream) {
    const float* left  = (const float*)d_in[0];
    const float* right = (const float*)d_in[1];
    float* out = (float*)d_out;

    dim3 grid(NROW / ROWS_PER_BLOCK);   // 1280 blocks
    dim3 block(512);                    // 8 waves, 8 consecutive h rows of one (b,g)
    hipLaunchKernelGGL(gwc_volume_kernel, grid, block, 0, stream,
                       left, right, out);
}